// Round 3
// baseline (256.244 us; speedup 1.0000x reference)
//
#include <hip/hip_runtime.h>

#define DIM   32
#define HID   64
#define TILES 8              // 16-cell tiles per wave

typedef __attribute__((ext_vector_type(8))) short bf16x8;   // 8 bf16 = 4 VGPRs
typedef __attribute__((ext_vector_type(4))) float f32x4;

// hardware packed f32x2 -> bf16x2 (RNE): result dword = (bf16(lo), bf16(hi))
__device__ __forceinline__ unsigned cvt_pk_bf16(float lo, float hi) {
    unsigned r;
    asm("v_cvt_pk_bf16_f32 %0, %1, %2" : "=v"(r) : "v"(lo), "v"(hi));
    return r;
}

// permlane32 swap via the intrinsic (distinct result regs guaranteed; the R2
// inline-asm "+v","+v" version let the compiler alias both operands to one reg).
// After: a = [a@lanes0-31, b@lanes0-31], b = [a@lanes32-63, b@lanes32-63]
__device__ __forceinline__ void plswap(unsigned &a, unsigned &b) {
    auto r = __builtin_amdgcn_permlane32_swap((int)a, (int)b, false, false);
    a = (unsigned)r[0];
    b = (unsigned)r[1];
}

// sum over the 4 quads (lanes c, c+16, c+32, c+48) -> all lanes get the total
__device__ __forceinline__ float quad_sum(float x) {
    unsigned a = __float_as_uint(x), b = __float_as_uint(x);
    plswap(a, b);
    float t = __uint_as_float(a) + __uint_as_float(b);   // x[l] + x[l^32]
    return t + __shfl_xor(t, 16, 64);                    // + 16-crossing (ds path, known-good)
}

union bfu { bf16x8 v; unsigned u[4]; };

__global__ __launch_bounds__(256, 4) void behavior_mfma(
    const float* __restrict__ g_in,   // [N, 32]
    const float* __restrict__ pot,    // [N]
    const float* __restrict__ W1,     // [33, 64]
    const float* __restrict__ b1,     // [64]
    const float* __restrict__ W2,     // [64, 32]
    const float* __restrict__ b2,     // [32]
    float* __restrict__ out)          // [N, 32]
{
    const int tid  = threadIdx.x;
    const int lane = tid & 63;
    const int quad = lane >> 4;        // 0..3
    const int mrow = lane & 15;        // 0..15
    const int wave = tid >> 6;         // 0..3

    // ---- W1 chunks as A-fragments of swapped GEMM1 (D = W1^T x^T).
    // A[m=hid_loc][k=dim] = W1[dim][nb*16+m]; lane: W1[(quad*8+j)*HID + nb*16+mrow]
    bf16x8 w1f[4];
    #pragma unroll
    for (int nb = 0; nb < 4; ++nb) {
        bfu t;
        #pragma unroll
        for (int jp = 0; jp < 4; ++jp)
            t.u[jp] = cvt_pk_bf16(W1[(quad * 8 + 2 * jp)     * HID + nb * 16 + mrow],
                                  W1[(quad * 8 + 2 * jp + 1) * HID + nb * 16 + mrow]);
        w1f[nb] = t.v;
    }
    // ---- W2 A-fragments with PERMUTED k-labeling to match the pl32-only h
    // redistribution: element j of lane (quad,mrow) holds hid
    //   hmap(quad,j) = (quad>>1)*16 + (quad&1)*4 + (j>>2)*8 + (j&3)
    bf16x8 w2f[2][2];
    #pragma unroll
    for (int kc = 0; kc < 2; ++kc)
        #pragma unroll
        for (int nc = 0; nc < 2; ++nc) {
            bfu t;
            #pragma unroll
            for (int jp = 0; jp < 4; ++jp) {
                const int j0 = 2 * jp;
                const int r0 = kc * 32 + (quad >> 1) * 16 + (quad & 1) * 4
                             + ((j0 >> 2) << 3) + (j0 & 3);
                t.u[jp] = cvt_pk_bf16(W2[r0 * DIM + nc * 16 + mrow],
                                      W2[(r0 + 1) * DIM + nc * 16 + mrow]);
            }
            w2f[kc][nc] = t.v;
        }
    // ---- identity A-fragment: A[m][k] = delta(k == nc*16+m) for 0.3*g pass-through
    // (this MFMA uses the NATURAL k=dim labeling; independent of w2f's permuted k)
    bf16x8 aid[2];
    #pragma unroll
    for (int nc = 0; nc < 2; ++nc) {
        bfu t;
        #pragma unroll
        for (int jp = 0; jp < 4; ++jp) {
            unsigned lo = (quad * 8 + 2 * jp     == nc * 16 + mrow) ? 0x00003F80u : 0u;
            unsigned hi = (quad * 8 + 2 * jp + 1 == nc * 16 + mrow) ? 0x3F800000u : 0u;
            t.u[jp] = lo | hi;
        }
        aid[nc] = t.v;
    }
    // ---- f32 bias path: c1[r] row = hid nb*16+quad*4+r, col = cell mrow.
    float w1pq[4][4], b1q[4][4];
    #pragma unroll
    for (int nb = 0; nb < 4; ++nb)
        #pragma unroll
        for (int r = 0; r < 4; ++r) {
            w1pq[nb][r] = W1[32 * HID + nb * 16 + quad * 4 + r];
            b1q[nb][r]  = b1[nb * 16 + quad * 4 + r];
        }
    // ---- b2 per output row (row = d_loc = quad*4 + r)
    float b2q[2][4];
    #pragma unroll
    for (int nc = 0; nc < 2; ++nc)
        #pragma unroll
        for (int r = 0; r < 4; ++r)
            b2q[nc][r] = b2[nc * 16 + quad * 4 + r];

    const long cell0 = ((long)blockIdx.x * 4 + wave) * (TILES * 16);

    // ---------- depth-2 global prefetch ----------
    float4 gA[2], gB[2]; float pV[2];
    auto loadT = [&](long cb, int s) {
        const float* gp = g_in + (cb + mrow) * DIM + quad * 8;
        gA[s] = ((const float4*)gp)[0];
        gB[s] = ((const float4*)gp)[1];
        pV[s] = pot[cb + mrow];                       // pot[cell=mrow]
    };
    loadT(cell0, 0);
    loadT(cell0 + 16, 1);

    #pragma unroll 2
    for (int t = 0; t < TILES; ++t) {
        const int s = t & 1;
        const long cb = cell0 + (long)t * 16;
        const float4 a = gA[s], b = gB[s];
        const float potv = pV[s];

        float gv[8] = {a.x, a.y, a.z, a.w, b.x, b.y, b.z, b.w};
        float cube[8];
        float tp = 0.f, sp = 0.f;
        #pragma unroll
        for (int j = 0; j < 8; ++j) {
            float gc = gv[j];
            float g2 = gc * gc;
            float g3 = g2 * gc;
            tp += g2;
            sp = fmaf(g3, g3, sp);
            cube[j] = g3;
        }
        tp = quad_sum(tp);
        sp = quad_sum(sp);
        const float scale = 0.1f * __builtin_amdgcn_sqrtf(tp) *
                            __builtin_amdgcn_rcpf(__builtin_amdgcn_sqrtf(sp) + 1e-8f);

        // x (with pattern) and 0.3*g as B-fragments: B[k=dim][n=cell]
        bfu xf, gf;
        #pragma unroll
        for (int jp = 0; jp < 4; ++jp) {
            xf.u[jp] = cvt_pk_bf16(fmaf(scale, cube[2 * jp],     gv[2 * jp]),
                                   fmaf(scale, cube[2 * jp + 1], gv[2 * jp + 1]));
            gf.u[jp] = cvt_pk_bf16(0.3f * gv[2 * jp], 0.3f * gv[2 * jp + 1]);
        }

        // prefetch tile t+2 into the slot we just consumed
        if (t + 2 < TILES) loadT(cb + 32, s);

        // ---- GEMM1' : s^T[hid_loc][cell]; f32 bias init; relu+pack.
        unsigned P[4][2];
        #pragma unroll
        for (int nb = 0; nb < 4; ++nb) {
            f32x4 c1;
            #pragma unroll
            for (int r = 0; r < 4; ++r)
                c1[r] = fmaf(potv, w1pq[nb][r], b1q[nb][r]);
            c1 = __builtin_amdgcn_mfma_f32_16x16x32_bf16(w1f[nb], xf.v, c1, 0, 0, 0);
            P[nb][0] = cvt_pk_bf16(fmaxf(c1[0], 0.f), fmaxf(c1[1], 0.f));
            P[nb][1] = cvt_pk_bf16(fmaxf(c1[2], 0.f), fmaxf(c1[3], 0.f));
        }

        // ---- redistribute h with pl32 ONLY; w2f's hmap matches this layout.
        bfu h0, h1;
        {
            unsigned x0 = P[0][0], y0 = P[1][0]; plswap(x0, y0);
            unsigned x1 = P[0][1], y1 = P[1][1]; plswap(x1, y1);
            h0.u[0] = x0; h0.u[1] = x1; h0.u[2] = y0; h0.u[3] = y1;
        }
        {
            unsigned x0 = P[2][0], y0 = P[3][0]; plswap(x0, y0);
            unsigned x1 = P[2][1], y1 = P[3][1]; plswap(x1, y1);
            h1.u[0] = x0; h1.u[1] = x1; h1.u[2] = y0; h1.u[3] = y1;
        }

        // ---- GEMM2' : out^T[d_loc][cell]; contiguous f32x4 NT store
        #pragma unroll
        for (int nc = 0; nc < 2; ++nc) {
            f32x4 c2 = {b2q[nc][0], b2q[nc][1], b2q[nc][2], b2q[nc][3]};
            c2 = __builtin_amdgcn_mfma_f32_16x16x32_bf16(aid[nc],    gf.v, c2, 0, 0, 0);
            c2 = __builtin_amdgcn_mfma_f32_16x16x32_bf16(w2f[0][nc], h0.v, c2, 0, 0, 0);
            c2 = __builtin_amdgcn_mfma_f32_16x16x32_bf16(w2f[1][nc], h1.v, c2, 0, 0, 0);
            f32x4* op = (f32x4*)(out + (cb + mrow) * DIM + nc * 16 + quad * 4);
            __builtin_nontemporal_store(c2, op);
        }
    }
}

extern "C" void kernel_launch(void* const* d_in, const int* in_sizes, int n_in,
                              void* d_out, int out_size, void* d_ws, size_t ws_size,
                              hipStream_t stream) {
    const float* g_in = (const float*)d_in[0];
    const float* pot  = (const float*)d_in[1];
    const float* W1   = (const float*)d_in[2];
    const float* b1   = (const float*)d_in[3];
    const float* W2   = (const float*)d_in[4];
    const float* b2   = (const float*)d_in[5];
    float* out = (float*)d_out;

    const int n_cells = in_sizes[1];                     // 1048576
    const int cells_per_block = 4 * TILES * 16;          // 512
    const int blocks = (n_cells + cells_per_block - 1) / cells_per_block;

    behavior_mfma<<<blocks, 256, 0, stream>>>(g_in, pot, W1, b1, W2, b2, out);
}